// Round 2
// baseline (370.756 us; speedup 1.0000x reference)
//
#include <hip/hip_runtime.h>
#include <hip/hip_bf16.h>

#define TPB 256

// Problem constants (fixed by setup_inputs): B=2,H=16,L=4096,D=64,M=64,chunk=128
constexpr int   Bc = 2, Hc = 16, Lc = 4096, Dc = 64, Mc = 64, CHc = 128;
constexpr int   NCc = Lc / CHc;         // 32 chunks
constexpr int   BHc = Bc * Hc;          // 32 heads total
constexpr float DNF    = 0.35355339059327373f;  // 64^-0.25
constexpr float RATIOF = 0.125f;                // 64^-0.5
constexpr float EPSF   = 1e-4f;
// diag coefficient = 0.5 * dn^2 = 0.0625

// ws layout (in floats)
constexpr long QP_OFF = 0;                       // 8388608 floats
constexpr long KP_OFF = 8388608;                 // 8388608
constexpr long KV_OFF = 16777216;                // 4194304
constexpr long KS_OFF = 20971520;                // 65536
constexpr long HM_OFF = 21037056;                // 32 (as unsigned)

__device__ __forceinline__ unsigned fordmap(float f) {
  unsigned u = __float_as_uint(f);
  return (u & 0x80000000u) ? ~u : (u | 0x80000000u);
}
__device__ __forceinline__ float fordunmap(unsigned u) {
  return __uint_as_float((u & 0x80000000u) ? (u & 0x7fffffffu) : ~u);
}

__global__ void k_init(unsigned* hmax) {
  int t = threadIdx.x;
  if (t < BHc) hmax[t] = 0u;
}

template <bool IS_Q>
__global__ __launch_bounds__(TPB) void k_feat(const float* __restrict__ x,
                                              const float* __restrict__ P,
                                              float* __restrict__ outp,
                                              unsigned* __restrict__ hmax) {
  __shared__ float xs[128 * 68];     // 128 rows, stride 68 (bank spread)
  __shared__ float Ps[64 * 64];
  __shared__ float diag_s[128];
  __shared__ unsigned bmax_s;
  const int t = threadIdx.x;
  const long rowbase = (long)blockIdx.x * 128;
  for (int i = t; i < 128 * 64; i += TPB) {
    int r = i >> 6, d = i & 63;
    xs[r * 68 + d] = x[rowbase * 64 + i];
  }
  for (int i = t; i < 64 * 64; i += TPB) Ps[i] = P[i];
  if (t == 0) bmax_s = 0u;
  __syncthreads();
  if (t < 128) {
    float s = 0.f;
#pragma unroll
    for (int d = 0; d < 64; d += 4) {
      float4 vv = *(const float4*)&xs[t * 68 + d];
      s += vv.x * vv.x + vv.y * vv.y + vv.z * vv.z + vv.w * vv.w;
    }
    diag_s[t] = 0.0625f * s;
  }
  __syncthreads();
  // thread tile: 4 rows x 8 m.  g = t&7 -> m0 = 8g ; rg = t>>3 -> r0 = 4*rg
  const int g = t & 7, rg = t >> 3;
  const int m0 = g * 8, r0 = rg * 4;
  float acc[4][8];
#pragma unroll
  for (int r = 0; r < 4; ++r)
#pragma unroll
    for (int j = 0; j < 8; ++j) acc[r][j] = 0.f;
  for (int d0 = 0; d0 < 64; d0 += 4) {
    float4 xv[4];
#pragma unroll
    for (int r = 0; r < 4; ++r) xv[r] = *(const float4*)&xs[(r0 + r) * 68 + d0];
#pragma unroll
    for (int dq = 0; dq < 4; ++dq) {
      float4 p0 = *(const float4*)&Ps[(d0 + dq) * 64 + m0];
      float4 p1 = *(const float4*)&Ps[(d0 + dq) * 64 + m0 + 4];
#pragma unroll
      for (int r = 0; r < 4; ++r) {
        float xd = reinterpret_cast<const float*>(&xv[r])[dq];
        acc[r][0] += xd * p0.x; acc[r][1] += xd * p0.y;
        acc[r][2] += xd * p0.z; acc[r][3] += xd * p0.w;
        acc[r][4] += xd * p1.x; acc[r][5] += xd * p1.y;
        acc[r][6] += xd * p1.z; acc[r][7] += xd * p1.w;
      }
    }
  }
#pragma unroll
  for (int r = 0; r < 4; ++r)
#pragma unroll
    for (int j = 0; j < 8; ++j) acc[r][j] *= DNF;   // dash values

  if constexpr (IS_Q) {
#pragma unroll
    for (int r = 0; r < 4; ++r) {
      float mx = acc[r][0];
#pragma unroll
      for (int j = 1; j < 8; ++j) mx = fmaxf(mx, acc[r][j]);
#pragma unroll
      for (int off = 1; off < 8; off <<= 1) mx = fmaxf(mx, __shfl_xor(mx, off));
      const float dg = diag_s[r0 + r];
      float4 o0, o1;
      float* o0f = (float*)&o0; float* o1f = (float*)&o1;
#pragma unroll
      for (int j = 0; j < 4; ++j) o0f[j] = RATIOF * (expf(acc[r][j] - dg - mx) + EPSF);
#pragma unroll
      for (int j = 0; j < 4; ++j) o1f[j] = RATIOF * (expf(acc[r][4 + j] - dg - mx) + EPSF);
      const long ob = (rowbase + r0 + r) * 64 + m0;
      *(float4*)&outp[ob] = o0;
      *(float4*)&outp[ob + 4] = o1;
    }
  } else {
    float tmax = acc[0][0];
#pragma unroll
    for (int r = 0; r < 4; ++r)
#pragma unroll
      for (int j = 0; j < 8; ++j) tmax = fmaxf(tmax, acc[r][j]);
#pragma unroll
    for (int r = 0; r < 4; ++r) {
      const float dg = diag_s[r0 + r];
      float4 o0, o1;
      float* o0f = (float*)&o0; float* o1f = (float*)&o1;
#pragma unroll
      for (int j = 0; j < 4; ++j) o0f[j] = acc[r][j] - dg;
#pragma unroll
      for (int j = 0; j < 4; ++j) o1f[j] = acc[r][4 + j] - dg;
      const long ob = (rowbase + r0 + r) * 64 + m0;
      *(float4*)&outp[ob] = o0;
      *(float4*)&outp[ob + 4] = o1;
    }
    atomicMax(&bmax_s, fordmap(tmax));
    __syncthreads();
    if (t == 0) atomicMax(&hmax[rowbase >> 12], bmax_s);
  }
}

__global__ __launch_bounds__(TPB) void k_kexp(float* __restrict__ kp,
                                              const unsigned* __restrict__ hmax) {
  const long i4 = (long)blockIdx.x * TPB + threadIdx.x;  // float4 index, 2097152 total
  const float stab = fordunmap(hmax[i4 >> 16]);          // 65536 float4 per head
  float4 vv = ((const float4*)kp)[i4];
  vv.x = RATIOF * (expf(vv.x - stab) + EPSF);
  vv.y = RATIOF * (expf(vv.y - stab) + EPSF);
  vv.z = RATIOF * (expf(vv.z - stab) + EPSF);
  vv.w = RATIOF * (expf(vv.w - stab) + EPSF);
  ((float4*)kp)[i4] = vv;
}

__global__ __launch_bounds__(TPB) void k_ckv(const float* __restrict__ kp,
                                             const float* __restrict__ v,
                                             float* __restrict__ kv,
                                             float* __restrict__ ks) {
  __shared__ float kps[128 * 66];
  __shared__ float vs[128 * 68];
  const int t = threadIdx.x;
  const int bhc = blockIdx.x;           // bh*32 + c
  const long base = (long)bhc * 8192;   // chunk is 128 contiguous rows of 64
  for (int i = t; i < 8192; i += TPB) {
    int r = i >> 6, d = i & 63;
    kps[r * 66 + d] = kp[base + i];
    vs[r * 68 + d]  = v[base + i];
  }
  __syncthreads();
  const int md = t & 31, dg = t >> 5;   // m0 = 2*md, dd0 = 8*dg
  const int m0 = md * 2, dd0 = dg * 8;
  float a0[8], a1[8];
#pragma unroll
  for (int i = 0; i < 8; ++i) { a0[i] = 0.f; a1[i] = 0.f; }
  for (int j = 0; j < 128; ++j) {
    float2 kk = *(const float2*)&kps[j * 66 + m0];
    float4 v0 = *(const float4*)&vs[j * 68 + dd0];
    float4 v1 = *(const float4*)&vs[j * 68 + dd0 + 4];
    a0[0] += kk.x * v0.x; a0[1] += kk.x * v0.y; a0[2] += kk.x * v0.z; a0[3] += kk.x * v0.w;
    a0[4] += kk.x * v1.x; a0[5] += kk.x * v1.y; a0[6] += kk.x * v1.z; a0[7] += kk.x * v1.w;
    a1[0] += kk.y * v0.x; a1[1] += kk.y * v0.y; a1[2] += kk.y * v0.z; a1[3] += kk.y * v0.w;
    a1[4] += kk.y * v1.x; a1[5] += kk.y * v1.y; a1[6] += kk.y * v1.z; a1[7] += kk.y * v1.w;
  }
  const long kvb = (long)bhc * 4096;
  *(float4*)&kv[kvb + (long)m0 * 64 + dd0]       = make_float4(a0[0], a0[1], a0[2], a0[3]);
  *(float4*)&kv[kvb + (long)m0 * 64 + dd0 + 4]   = make_float4(a0[4], a0[5], a0[6], a0[7]);
  *(float4*)&kv[kvb + (long)(m0 + 1) * 64 + dd0]     = make_float4(a1[0], a1[1], a1[2], a1[3]);
  *(float4*)&kv[kvb + (long)(m0 + 1) * 64 + dd0 + 4] = make_float4(a1[4], a1[5], a1[6], a1[7]);
  if (t < 64) {
    float s = 0.f;
    for (int j = 0; j < 128; ++j) s += kps[j * 66 + t];
    ks[bhc * 64 + t] = s;
  }
}

__global__ void k_scan_kv(float* __restrict__ kv) {
  const int tid = blockIdx.x * TPB + threadIdx.x;  // 131072 = 32 heads * 4096 (m,d)
  const int bh = tid >> 12, rem = tid & 4095;
  float run = 0.f;
  for (int c = 0; c < NCc; ++c) {
    const long idx = ((long)(bh * NCc + c)) * 4096 + rem;
    const float val = kv[idx];
    kv[idx] = run;
    run += val;
  }
}

__global__ void k_scan_ks(float* __restrict__ ks) {
  const int tid = blockIdx.x * TPB + threadIdx.x;  // 2048 = 32 heads * 64 m
  if (tid >= BHc * 64) return;
  const int bh = tid >> 6, m = tid & 63;
  float run = 0.f;
  for (int c = 0; c < NCc; ++c) {
    const int idx = (bh * NCc + c) * 64 + m;
    const float val = ks[idx];
    ks[idx] = run;
    run += val;
  }
}

__global__ __launch_bounds__(TPB) void k_attn(const float* __restrict__ qp,
                                              const float* __restrict__ kp,
                                              const float* __restrict__ v,
                                              const float* __restrict__ kvp,
                                              const float* __restrict__ ksp,
                                              float* __restrict__ outp) {
  __shared__ float qs[64 * 68];     // this half's 64 q rows
  __shared__ float kls[128 * 68];   // kp rows 0..JC
  __shared__ float vls[128 * 68];   // v rows 0..JC
  __shared__ float Ss[64 * 132];    // masked scores
  __shared__ float kvs[64 * 64];    // kv_prev
  __shared__ float ksps[64];
  __shared__ float dens[64];
  const int t = threadIdx.x;
  const int bid = blockIdx.x;
  const int half = bid & 1;
  const int bhc = bid >> 1;
  const long cbase = (long)bhc * 8192;
  const int rb = half * 64;          // row offset within chunk
  const int JC = half ? 128 : 64;    // causal: lower half only needs first 64 k/v rows
  for (int i = t; i < 4096; i += TPB) {
    int r = i >> 6, d = i & 63;
    qs[r * 68 + d] = qp[cbase + (long)(rb + r) * 64 + d];
  }
  for (int i = t; i < JC * 64; i += TPB) {
    int r = i >> 6, d = i & 63;
    kls[r * 68 + d] = kp[cbase + i];
    vls[r * 68 + d] = v[cbase + i];
  }
  for (int i = t; i < 4096; i += TPB) kvs[i] = kvp[(long)bhc * 4096 + i];
  if (t < 64) ksps[t] = ksp[bhc * 64 + t];
  __syncthreads();
  // ---- scores S (64 rows x JC cols), tile 4 rows x 8 cols ----
  {
    const int rg = t & 15, jg = t >> 4;
    if (jg * 8 < JC) {
      const int r0 = rg * 4, j0 = jg * 8;
      float acc[4][8];
#pragma unroll
      for (int r = 0; r < 4; ++r)
#pragma unroll
        for (int j = 0; j < 8; ++j) acc[r][j] = 0.f;
      for (int m0 = 0; m0 < 64; m0 += 4) {
        float4 kq[8];
#pragma unroll
        for (int jj = 0; jj < 8; ++jj) kq[jj] = *(const float4*)&kls[(j0 + jj) * 68 + m0];
#pragma unroll
        for (int r = 0; r < 4; ++r) {
          float4 qv = *(const float4*)&qs[(r0 + r) * 68 + m0];
#pragma unroll
          for (int jj = 0; jj < 8; ++jj)
            acc[r][jj] += qv.x * kq[jj].x + qv.y * kq[jj].y + qv.z * kq[jj].z + qv.w * kq[jj].w;
        }
      }
#pragma unroll
      for (int r = 0; r < 4; ++r) {
        const int gi = rb + r0 + r;
        float4 s0, s1;
        float* s0f = (float*)&s0; float* s1f = (float*)&s1;
#pragma unroll
        for (int jj = 0; jj < 4; ++jj) s0f[jj] = (j0 + jj <= gi) ? acc[r][jj] : 0.f;
#pragma unroll
        for (int jj = 0; jj < 4; ++jj) s1f[jj] = (j0 + 4 + jj <= gi) ? acc[r][4 + jj] : 0.f;
        *(float4*)&Ss[(r0 + r) * 132 + j0] = s0;
        *(float4*)&Ss[(r0 + r) * 132 + j0 + 4] = s1;
      }
    }
  }
  __syncthreads();
  // ---- denominators ----
  if (t < 64) {
    float s = 0.f;
    for (int j = 0; j < JC; j += 4) {
      float4 sv = *(const float4*)&Ss[t * 132 + j];
      s += sv.x + sv.y + sv.z + sv.w;
    }
#pragma unroll
    for (int m = 0; m < 64; m += 4) {
      float4 qv = *(const float4*)&qs[t * 68 + m];
      float4 kk = *(const float4*)&ksps[m];
      s += qv.x * kk.x + qv.y * kk.y + qv.z * kk.z + qv.w * kk.w;
    }
    dens[t] = s;
  }
  __syncthreads();
  // ---- output: (S·v + qp·kv_prev)/den, tile 4 rows x 4 dd ----
  {
    const int rg = t >> 4, dg = t & 15;
    const int r0 = rg * 4, dd0 = dg * 4;
    float acc[4][4];
#pragma unroll
    for (int r = 0; r < 4; ++r)
#pragma unroll
      for (int q = 0; q < 4; ++q) acc[r][q] = 0.f;
    for (int j0 = 0; j0 < JC; j0 += 4) {
      float4 sv[4];
#pragma unroll
      for (int r = 0; r < 4; ++r) sv[r] = *(const float4*)&Ss[(r0 + r) * 132 + j0];
#pragma unroll
      for (int q = 0; q < 4; ++q) {
        float4 vv = *(const float4*)&vls[(j0 + q) * 68 + dd0];
#pragma unroll
        for (int r = 0; r < 4; ++r) {
          const float sc = reinterpret_cast<const float*>(&sv[r])[q];
          acc[r][0] += sc * vv.x; acc[r][1] += sc * vv.y;
          acc[r][2] += sc * vv.z; acc[r][3] += sc * vv.w;
        }
      }
    }
#pragma unroll
    for (int m0 = 0; m0 < 64; m0 += 4) {
      float4 qv4[4];
#pragma unroll
      for (int r = 0; r < 4; ++r) qv4[r] = *(const float4*)&qs[(r0 + r) * 68 + m0];
#pragma unroll
      for (int q = 0; q < 4; ++q) {
        float4 kvv = *(const float4*)&kvs[(m0 + q) * 64 + dd0];
#pragma unroll
        for (int r = 0; r < 4; ++r) {
          const float sc = reinterpret_cast<const float*>(&qv4[r])[q];
          acc[r][0] += sc * kvv.x; acc[r][1] += sc * kvv.y;
          acc[r][2] += sc * kvv.z; acc[r][3] += sc * kvv.w;
        }
      }
    }
#pragma unroll
    for (int r = 0; r < 4; ++r) {
      const float inv = 1.f / dens[r0 + r];
      float4 ov;
      ov.x = acc[r][0] * inv; ov.y = acc[r][1] * inv;
      ov.z = acc[r][2] * inv; ov.w = acc[r][3] * inv;
      const long ob = cbase + (long)(rb + r0 + r) * 64 + dd0;
      *(float4*)&outp[ob] = ov;
    }
  }
}

extern "C" void kernel_launch(void* const* d_in, const int* in_sizes, int n_in,
                              void* d_out, int out_size, void* d_ws, size_t ws_size,
                              hipStream_t stream) {
  const float* q = (const float*)d_in[0];
  const float* k = (const float*)d_in[1];
  const float* v = (const float*)d_in[2];
  const float* P = (const float*)d_in[3];
  // d_in[4] = chunk_size (=128, hardcoded)
  float* ws = (float*)d_ws;
  float* qp = ws + QP_OFF;
  float* kp = ws + KP_OFF;
  float* kv = ws + KV_OFF;
  float* ks = ws + KS_OFF;
  unsigned* hmax = (unsigned*)(ws + HM_OFF);
  float* out = (float*)d_out;

  k_init<<<1, 64, 0, stream>>>(hmax);
  k_feat<true><<<dim3(1024), dim3(TPB), 0, stream>>>(q, P, qp, nullptr);
  k_feat<false><<<dim3(1024), dim3(TPB), 0, stream>>>(k, P, kp, hmax);
  k_kexp<<<dim3(8192), dim3(TPB), 0, stream>>>(kp, hmax);
  k_ckv<<<dim3(1024), dim3(TPB), 0, stream>>>(kp, v, kv, ks);
  k_scan_kv<<<dim3(512), dim3(TPB), 0, stream>>>(kv);
  k_scan_ks<<<dim3(8), dim3(TPB), 0, stream>>>(ks);
  k_attn<<<dim3(2048), dim3(TPB), 0, stream>>>(qp, kp, v, kv, ks, out);
}

// Round 3
// 266.574 us; speedup vs baseline: 1.3908x; 1.3908x over previous
//
#include <hip/hip_runtime.h>
#include <hip/hip_bf16.h>

#define TPB 256

// Problem constants (fixed by setup_inputs): B=2,H=16,L=4096,D=64,M=64,chunk=128
constexpr int   Bc = 2, Hc = 16, Lc = 4096, Dc = 64, Mc = 64, CHc = 128;
constexpr int   NCc = Lc / CHc;         // 32 chunks
constexpr int   BHc = Bc * Hc;          // 32 heads total
constexpr float DNF    = 0.35355339059327373f;  // 64^-0.25
constexpr float RATIOF = 0.125f;                // 64^-0.5
constexpr float EPSF   = 1e-4f;
// diag coefficient = 0.5 * dn^2 = 0.0625

// ws layout (in floats)
constexpr long QP_OFF = 0;                       // 8388608 floats
constexpr long KP_OFF = 8388608;                 // 8388608
constexpr long KV_OFF = 16777216;                // 4194304
constexpr long KS_OFF = 20971520;                // 65536
constexpr long HM_OFF = 21037056;                // 32 (as unsigned)

typedef __attribute__((ext_vector_type(8))) short bf16x8;
typedef __attribute__((ext_vector_type(4))) float f32x4;

__device__ __forceinline__ unsigned fordmap(float f) {
  unsigned u = __float_as_uint(f);
  return (u & 0x80000000u) ? ~u : (u | 0x80000000u);
}
__device__ __forceinline__ float fordunmap(unsigned u) {
  return __uint_as_float((u & 0x80000000u) ? (u & 0x7fffffffu) : ~u);
}
__device__ __forceinline__ unsigned pk2(float a, float b) {
  union { __hip_bfloat16 h; unsigned short u; } ca, cb;
  ca.h = __float2bfloat16(a); cb.h = __float2bfloat16(b);
  return ((unsigned)cb.u << 16) | (unsigned)ca.u;
}
__device__ __forceinline__ short f2bf(float a) {
  union { __hip_bfloat16 h; short s; } c; c.h = __float2bfloat16(a); return c.s;
}
__device__ __forceinline__ float uplo(unsigned u) { return __uint_as_float(u << 16); }
__device__ __forceinline__ float uphi(unsigned u) { return __uint_as_float(u & 0xffff0000u); }

__global__ void k_init(unsigned* hmax) {
  int t = threadIdx.x;
  if (t < BHc) hmax[t] = 0u;
}

template <bool IS_Q>
__global__ __launch_bounds__(TPB) void k_feat(const float* __restrict__ x,
                                              const float* __restrict__ P,
                                              float* __restrict__ outp,
                                              unsigned* __restrict__ hmax) {
  __shared__ float xs[128 * 68];     // 128 rows, stride 68 (bank spread)
  __shared__ float Ps[64 * 64];
  __shared__ float diag_s[128];
  __shared__ unsigned bmax_s;
  const int t = threadIdx.x;
  const long rowbase = (long)blockIdx.x * 128;
  for (int i = t; i < 128 * 64; i += TPB) {
    int r = i >> 6, d = i & 63;
    xs[r * 68 + d] = x[rowbase * 64 + i];
  }
  for (int i = t; i < 64 * 64; i += TPB) Ps[i] = P[i];
  if (t == 0) bmax_s = 0u;
  __syncthreads();
  if (t < 128) {
    float s = 0.f;
#pragma unroll
    for (int d = 0; d < 64; d += 4) {
      float4 vv = *(const float4*)&xs[t * 68 + d];
      s += vv.x * vv.x + vv.y * vv.y + vv.z * vv.z + vv.w * vv.w;
    }
    diag_s[t] = 0.0625f * s;
  }
  __syncthreads();
  // thread tile: 4 rows x 8 m.  g = t&7 -> m0 = 8g ; rg = t>>3 -> r0 = 4*rg
  const int g = t & 7, rg = t >> 3;
  const int m0 = g * 8, r0 = rg * 4;
  float acc[4][8];
#pragma unroll
  for (int r = 0; r < 4; ++r)
#pragma unroll
    for (int j = 0; j < 8; ++j) acc[r][j] = 0.f;
  for (int d0 = 0; d0 < 64; d0 += 4) {
    float4 xv[4];
#pragma unroll
    for (int r = 0; r < 4; ++r) xv[r] = *(const float4*)&xs[(r0 + r) * 68 + d0];
#pragma unroll
    for (int dq = 0; dq < 4; ++dq) {
      float4 p0 = *(const float4*)&Ps[(d0 + dq) * 64 + m0];
      float4 p1 = *(const float4*)&Ps[(d0 + dq) * 64 + m0 + 4];
#pragma unroll
      for (int r = 0; r < 4; ++r) {
        float xd = reinterpret_cast<const float*>(&xv[r])[dq];
        acc[r][0] += xd * p0.x; acc[r][1] += xd * p0.y;
        acc[r][2] += xd * p0.z; acc[r][3] += xd * p0.w;
        acc[r][4] += xd * p1.x; acc[r][5] += xd * p1.y;
        acc[r][6] += xd * p1.z; acc[r][7] += xd * p1.w;
      }
    }
  }
#pragma unroll
  for (int r = 0; r < 4; ++r)
#pragma unroll
    for (int j = 0; j < 8; ++j) acc[r][j] *= DNF;   // dash values

  if constexpr (IS_Q) {
#pragma unroll
    for (int r = 0; r < 4; ++r) {
      float mx = acc[r][0];
#pragma unroll
      for (int j = 1; j < 8; ++j) mx = fmaxf(mx, acc[r][j]);
#pragma unroll
      for (int off = 1; off < 8; off <<= 1) mx = fmaxf(mx, __shfl_xor(mx, off));
      const float dg = diag_s[r0 + r];
      float4 o0, o1;
      float* o0f = (float*)&o0; float* o1f = (float*)&o1;
#pragma unroll
      for (int j = 0; j < 4; ++j) o0f[j] = RATIOF * (expf(acc[r][j] - dg - mx) + EPSF);
#pragma unroll
      for (int j = 0; j < 4; ++j) o1f[j] = RATIOF * (expf(acc[r][4 + j] - dg - mx) + EPSF);
      const long ob = (rowbase + r0 + r) * 64 + m0;
      *(float4*)&outp[ob] = o0;
      *(float4*)&outp[ob + 4] = o1;
    }
  } else {
    float tmax = acc[0][0];
#pragma unroll
    for (int r = 0; r < 4; ++r)
#pragma unroll
      for (int j = 0; j < 8; ++j) tmax = fmaxf(tmax, acc[r][j]);
#pragma unroll
    for (int r = 0; r < 4; ++r) {
      const float dg = diag_s[r0 + r];
      float4 o0, o1;
      float* o0f = (float*)&o0; float* o1f = (float*)&o1;
#pragma unroll
      for (int j = 0; j < 4; ++j) o0f[j] = acc[r][j] - dg;
#pragma unroll
      for (int j = 0; j < 4; ++j) o1f[j] = acc[r][4 + j] - dg;
      const long ob = (rowbase + r0 + r) * 64 + m0;
      *(float4*)&outp[ob] = o0;
      *(float4*)&outp[ob + 4] = o1;
    }
    atomicMax(&bmax_s, fordmap(tmax));
    __syncthreads();
    if (t == 0) atomicMax(&hmax[rowbase >> 12], bmax_s);
  }
}

__global__ __launch_bounds__(TPB) void k_kexp(float* __restrict__ kp,
                                              const unsigned* __restrict__ hmax) {
  const long i4 = (long)blockIdx.x * TPB + threadIdx.x;  // float4 index, 2097152 total
  const float stab = fordunmap(hmax[i4 >> 16]);          // 65536 float4 per head
  float4 vv = ((const float4*)kp)[i4];
  vv.x = RATIOF * (expf(vv.x - stab) + EPSF);
  vv.y = RATIOF * (expf(vv.y - stab) + EPSF);
  vv.z = RATIOF * (expf(vv.z - stab) + EPSF);
  vv.w = RATIOF * (expf(vv.w - stab) + EPSF);
  ((float4*)kp)[i4] = vv;
}

__global__ __launch_bounds__(TPB) void k_ckv(const float* __restrict__ kp,
                                             const float* __restrict__ v,
                                             float* __restrict__ kv,
                                             float* __restrict__ ks) {
  __shared__ float kps[128 * 66];
  __shared__ float vs[128 * 68];
  const int t = threadIdx.x;
  const int bhc = blockIdx.x;           // bh*32 + c
  const long base = (long)bhc * 8192;   // chunk is 128 contiguous rows of 64
  for (int i = t; i < 8192; i += TPB) {
    int r = i >> 6, d = i & 63;
    kps[r * 66 + d] = kp[base + i];
    vs[r * 68 + d]  = v[base + i];
  }
  __syncthreads();
  const int md = t & 31, dg = t >> 5;   // m0 = 2*md, dd0 = 8*dg
  const int m0 = md * 2, dd0 = dg * 8;
  float a0[8], a1[8];
#pragma unroll
  for (int i = 0; i < 8; ++i) { a0[i] = 0.f; a1[i] = 0.f; }
  for (int j = 0; j < 128; ++j) {
    float2 kk = *(const float2*)&kps[j * 66 + m0];
    float4 v0 = *(const float4*)&vs[j * 68 + dd0];
    float4 v1 = *(const float4*)&vs[j * 68 + dd0 + 4];
    a0[0] += kk.x * v0.x; a0[1] += kk.x * v0.y; a0[2] += kk.x * v0.z; a0[3] += kk.x * v0.w;
    a0[4] += kk.x * v1.x; a0[5] += kk.x * v1.y; a0[6] += kk.x * v1.z; a0[7] += kk.x * v1.w;
    a1[0] += kk.y * v0.x; a1[1] += kk.y * v0.y; a1[2] += kk.y * v0.z; a1[3] += kk.y * v0.w;
    a1[4] += kk.y * v1.x; a1[5] += kk.y * v1.y; a1[6] += kk.y * v1.z; a1[7] += kk.y * v1.w;
  }
  const long kvb = (long)bhc * 4096;
  *(float4*)&kv[kvb + (long)m0 * 64 + dd0]       = make_float4(a0[0], a0[1], a0[2], a0[3]);
  *(float4*)&kv[kvb + (long)m0 * 64 + dd0 + 4]   = make_float4(a0[4], a0[5], a0[6], a0[7]);
  *(float4*)&kv[kvb + (long)(m0 + 1) * 64 + dd0]     = make_float4(a1[0], a1[1], a1[2], a1[3]);
  *(float4*)&kv[kvb + (long)(m0 + 1) * 64 + dd0 + 4] = make_float4(a1[4], a1[5], a1[6], a1[7]);
  if (t < 64) {
    float s = 0.f;
    for (int j = 0; j < 128; ++j) s += kps[j * 66 + t];
    ks[bhc * 64 + t] = s;
  }
}

__global__ void k_scan_kv(float* __restrict__ kv) {
  const int tid = blockIdx.x * TPB + threadIdx.x;  // 131072 = 32 heads * 4096 (m,d)
  const int bh = tid >> 12, rem = tid & 4095;
  float run = 0.f;
  for (int c = 0; c < NCc; ++c) {
    const long idx = ((long)(bh * NCc + c)) * 4096 + rem;
    const float val = kv[idx];
    kv[idx] = run;
    run += val;
  }
}

__global__ void k_scan_ks(float* __restrict__ ks) {
  const int tid = blockIdx.x * TPB + threadIdx.x;  // 2048 = 32 heads * 64 m
  if (tid >= BHc * 64) return;
  const int bh = tid >> 6, m = tid & 63;
  float run = 0.f;
  for (int c = 0; c < NCc; ++c) {
    const int idx = (bh * NCc + c) * 64 + m;
    const float val = ks[idx];
    ks[idx] = run;
    run += val;
  }
}

// MFMA chunk-attention: one block per (b,h,chunk). 256 threads = 4 waves.
// Layouts (bf16 shorts in LDS, strides chosen 16B-aligned & 2-way-bank-max):
//   Qs[r][m]  128x72   A-frags rows    Ks[j][m] 128x72  B-frags (Q.K^T)
//   Vt[d][j]   64x136  B-frags (P.V)   KVt[d][m] 64x72  B-frags (Q.KV)
//   Ps[i][j]  128x136  masked scores (C/D->A round trip through LDS)
__global__ __launch_bounds__(TPB) void k_attn(const float* __restrict__ qp,
                                              const float* __restrict__ kp,
                                              const float* __restrict__ v,
                                              const float* __restrict__ kvp,
                                              const float* __restrict__ ksp,
                                              float* __restrict__ outp) {
  __shared__ short Qs[128 * 72];
  __shared__ short Ks[128 * 72];
  __shared__ short Vt[64 * 136];
  __shared__ short KVt[64 * 72];
  __shared__ short Ps[128 * 136];
  __shared__ float dens[128];
  __shared__ float kss[64];
  const int t = threadIdx.x;
  const int bhc = blockIdx.x;
  const long cbase = (long)bhc * 8192;
  const long kvbase = (long)bhc * 4096;
  // ---- stage + convert to bf16 ----
  for (int i = t; i < 4096; i += TPB) {           // qp,kp: 4096 float2 each
    int r = i >> 5, d2 = (i & 31) * 2;
    float2 qv = *(const float2*)&qp[cbase + r * 64 + d2];
    float2 kv2 = *(const float2*)&kp[cbase + r * 64 + d2];
    *(unsigned*)&Qs[r * 72 + d2] = pk2(qv.x, qv.y);
    *(unsigned*)&Ks[r * 72 + d2] = pk2(kv2.x, kv2.y);
  }
  for (int i = t; i < 4096; i += TPB) {           // v transposed: pair rows
    int jp = i >> 6, d = i & 63;
    float a = v[cbase + (2 * jp) * 64 + d];
    float b = v[cbase + (2 * jp + 1) * 64 + d];
    *(unsigned*)&Vt[d * 136 + 2 * jp] = pk2(a, b);
  }
  for (int i = t; i < 2048; i += TPB) {           // kv transposed: pair rows
    int mp = i >> 6, d = i & 63;
    float a = kvp[kvbase + (2 * mp) * 64 + d];
    float b = kvp[kvbase + (2 * mp + 1) * 64 + d];
    *(unsigned*)&KVt[d * 72 + 2 * mp] = pk2(a, b);
  }
  if (t < 64) kss[t] = ksp[bhc * 64 + t];
  // zero the pad tile right of the diagonal for even row-tiles (phase-2 K-loop
  // rounds to 32-chunks and reads it)
  for (int i = t; i < 1024; i += TPB) {
    int tp = i >> 8, rr = (i >> 4) & 15, cc = i & 15;
    Ps[(tp * 32 + rr) * 136 + tp * 32 + 16 + cc] = 0;
  }
  __syncthreads();

  const int w = t >> 6, lane = t & 63;
  const int lrow = lane & 15, quad = lane >> 4;
  const int rts[2] = {w, 7 - w};                  // balanced causal pairing
  // ---- phase 1: S = Q.K^T (causal tiles), mask, bf16 -> Ps ----
#pragma unroll
  for (int s = 0; s < 2; ++s) {
    const int ri = rts[s];
    const bf16x8 a0 = *(const bf16x8*)&Qs[(ri * 16 + lrow) * 72 + quad * 8];
    const bf16x8 a1 = *(const bf16x8*)&Qs[(ri * 16 + lrow) * 72 + 32 + quad * 8];
    for (int cj = 0; cj <= ri; ++cj) {
      const bf16x8 b0 = *(const bf16x8*)&Ks[(cj * 16 + lrow) * 72 + quad * 8];
      const bf16x8 b1 = *(const bf16x8*)&Ks[(cj * 16 + lrow) * 72 + 32 + quad * 8];
      f32x4 c = {0.f, 0.f, 0.f, 0.f};
      c = __builtin_amdgcn_mfma_f32_16x16x32_bf16(a0, b0, c, 0, 0, 0);
      c = __builtin_amdgcn_mfma_f32_16x16x32_bf16(a1, b1, c, 0, 0, 0);
      if (cj == ri) {                              // diagonal mask: col<=row
#pragma unroll
        for (int r = 0; r < 4; ++r)
          if (lrow > quad * 4 + r) c[r] = 0.f;
      }
      const int colb = cj * 16 + lrow;
#pragma unroll
      for (int r = 0; r < 4; ++r)
        Ps[(ri * 16 + quad * 4 + r) * 136 + colb] = f2bf(c[r]);
    }
  }
  __syncthreads();
  // ---- denominators: rowsum(P) + Q.ks_prev ----
  if (t < 128) {
    const int row = t;
    float s = 0.f;
    const int nch = (row >> 3) + 1;               // 8-col chunks; tail is masked zeros
    for (int ch = 0; ch < nch; ++ch) {
      uint4 u = *(const uint4*)&Ps[row * 136 + ch * 8];
      s += uplo(u.x) + uphi(u.x) + uplo(u.y) + uphi(u.y)
         + uplo(u.z) + uphi(u.z) + uplo(u.w) + uphi(u.w);
    }
#pragma unroll
    for (int ch = 0; ch < 8; ++ch) {
      uint4 u = *(const uint4*)&Qs[row * 72 + ch * 8];
      float4 k0 = *(const float4*)&kss[ch * 8];
      float4 k1 = *(const float4*)&kss[ch * 8 + 4];
      s += uplo(u.x) * k0.x + uphi(u.x) * k0.y + uplo(u.y) * k0.z + uphi(u.y) * k0.w
         + uplo(u.z) * k1.x + uphi(u.z) * k1.y + uplo(u.w) * k1.z + uphi(u.w) * k1.w;
    }
    dens[row] = s;
  }
  __syncthreads();
  // ---- phase 2: out = (P.V + Q.KV_prev) / den ----
#pragma unroll
  for (int s = 0; s < 2; ++s) {
    const int ri = rts[s];
    f32x4 acc0 = {0.f,0.f,0.f,0.f}, acc1 = {0.f,0.f,0.f,0.f};
    f32x4 acc2 = {0.f,0.f,0.f,0.f}, acc3 = {0.f,0.f,0.f,0.f};
    const int nj = (ri + 2) >> 1;                 // causal 32-wide K chunks
    for (int jc = 0; jc < nj; ++jc) {
      const bf16x8 a = *(const bf16x8*)&Ps[(ri * 16 + lrow) * 136 + jc * 32 + quad * 8];
      const bf16x8 b0 = *(const bf16x8*)&Vt[(lrow) * 136 + jc * 32 + quad * 8];
      const bf16x8 b1 = *(const bf16x8*)&Vt[(16 + lrow) * 136 + jc * 32 + quad * 8];
      const bf16x8 b2 = *(const bf16x8*)&Vt[(32 + lrow) * 136 + jc * 32 + quad * 8];
      const bf16x8 b3 = *(const bf16x8*)&Vt[(48 + lrow) * 136 + jc * 32 + quad * 8];
      acc0 = __builtin_amdgcn_mfma_f32_16x16x32_bf16(a, b0, acc0, 0, 0, 0);
      acc1 = __builtin_amdgcn_mfma_f32_16x16x32_bf16(a, b1, acc1, 0, 0, 0);
      acc2 = __builtin_amdgcn_mfma_f32_16x16x32_bf16(a, b2, acc2, 0, 0, 0);
      acc3 = __builtin_amdgcn_mfma_f32_16x16x32_bf16(a, b3, acc3, 0, 0, 0);
    }
#pragma unroll
    for (int kc = 0; kc < 2; ++kc) {
      const bf16x8 a = *(const bf16x8*)&Qs[(ri * 16 + lrow) * 72 + kc * 32 + quad * 8];
      const bf16x8 b0 = *(const bf16x8*)&KVt[(lrow) * 72 + kc * 32 + quad * 8];
      const bf16x8 b1 = *(const bf16x8*)&KVt[(16 + lrow) * 72 + kc * 32 + quad * 8];
      const bf16x8 b2 = *(const bf16x8*)&KVt[(32 + lrow) * 72 + kc * 32 + quad * 8];
      const bf16x8 b3 = *(const bf16x8*)&KVt[(48 + lrow) * 72 + kc * 32 + quad * 8];
      acc0 = __builtin_amdgcn_mfma_f32_16x16x32_bf16(a, b0, acc0, 0, 0, 0);
      acc1 = __builtin_amdgcn_mfma_f32_16x16x32_bf16(a, b1, acc1, 0, 0, 0);
      acc2 = __builtin_amdgcn_mfma_f32_16x16x32_bf16(a, b2, acc2, 0, 0, 0);
      acc3 = __builtin_amdgcn_mfma_f32_16x16x32_bf16(a, b3, acc3, 0, 0, 0);
    }
#pragma unroll
    for (int r = 0; r < 4; ++r) {
      const int row = ri * 16 + quad * 4 + r;
      const float inv = 1.f / dens[row];
      const long ob = cbase + (long)row * 64 + lrow;
      outp[ob]      = acc0[r] * inv;
      outp[ob + 16] = acc1[r] * inv;
      outp[ob + 32] = acc2[r] * inv;
      outp[ob + 48] = acc3[r] * inv;
    }
  }
}

extern "C" void kernel_launch(void* const* d_in, const int* in_sizes, int n_in,
                              void* d_out, int out_size, void* d_ws, size_t ws_size,
                              hipStream_t stream) {
  const float* q = (const float*)d_in[0];
  const float* k = (const float*)d_in[1];
  const float* v = (const float*)d_in[2];
  const float* P = (const float*)d_in[3];
  // d_in[4] = chunk_size (=128, hardcoded)
  float* ws = (float*)d_ws;
  float* qp = ws + QP_OFF;
  float* kp = ws + KP_OFF;
  float* kv = ws + KV_OFF;
  float* ks = ws + KS_OFF;
  unsigned* hmax = (unsigned*)(ws + HM_OFF);
  float* out = (float*)d_out;

  k_init<<<1, 64, 0, stream>>>(hmax);
  k_feat<true><<<dim3(1024), dim3(TPB), 0, stream>>>(q, P, qp, nullptr);
  k_feat<false><<<dim3(1024), dim3(TPB), 0, stream>>>(k, P, kp, hmax);
  k_kexp<<<dim3(8192), dim3(TPB), 0, stream>>>(kp, hmax);
  k_ckv<<<dim3(1024), dim3(TPB), 0, stream>>>(kp, v, kv, ks);
  k_scan_kv<<<dim3(512), dim3(TPB), 0, stream>>>(kv);
  k_scan_ks<<<dim3(8), dim3(TPB), 0, stream>>>(ks);
  k_attn<<<dim3(1024), dim3(TPB), 0, stream>>>(qp, kp, v, kv, ks, out);
}